// Round 8
// baseline (2183.021 us; speedup 1.0000x reference)
//
#include <hip/hip_runtime.h>

typedef __attribute__((ext_vector_type(8))) short bf16x8;
typedef __attribute__((ext_vector_type(4))) float f32x4;
typedef __attribute__((ext_vector_type(4))) unsigned int u32x4;
typedef const __attribute__((address_space(1))) void* gas_ptr;
typedef __attribute__((address_space(3))) void* las_ptr;

__device__ __forceinline__ unsigned short f2bf(float f) {
  unsigned int u = __float_as_uint(f);
  return (unsigned short)((u + 0x7fffu + ((u >> 16) & 1u)) >> 16);  // RNE
}
__device__ __forceinline__ unsigned int cvt_pk_bf16(float a, float b) {
  unsigned int r;
  asm volatile("v_cvt_pk_bf16_f32 %0, %1, %2" : "=v"(r) : "v"(a), "v"(b));
  return r;
}
__device__ __forceinline__ float sigm(float x) { return 1.0f / (1.0f + __expf(-x)); }
__device__ __forceinline__ unsigned umin2(unsigned a, unsigned b) { return a < b ? a : b; }

// device-coherent (sc0 sc1) store: relaxed agent atomic bypasses L1/L2, lands at IF.
__device__ __forceinline__ void st_cv(unsigned int* p, unsigned int v) {
  __hip_atomic_store(p, v, __ATOMIC_RELAXED, __HIP_MEMORY_SCOPE_AGENT);
}

// ---------------- K1: h0 -> bf16 double-buffered state, zero barrier ----------------
__global__ __launch_bounds__(256) void init_kernel(
    const float* __restrict__ h0_in,
    unsigned short* __restrict__ h0buf, unsigned short* __restrict__ h1buf,
    int* __restrict__ bar)
{
  const int j = blockIdx.x * 256 + threadIdx.x;   // 0..32767
  if (j < 768) bar[j] = 0;
  h0buf[j] = f2bf(h0_in[j]);                 // layer0 h -> h0buf slot0
  h1buf[32768 + j] = f2bf(h0_in[32768 + j]); // layer1 h -> h1buf slot1
}

// ---------------- K1b: gather emb[tokens] -> xemb bf16 [128*32][1024] ----------------
__global__ __launch_bounds__(256) void gather_emb(
    const int* __restrict__ tokens, const float* __restrict__ etab,
    unsigned short* __restrict__ xemb)
{
  const int r = blockIdx.x;                       // t*32 + b
  const float* src = etab + (size_t)tokens[r] * 1024;
  const int q = threadIdx.x * 4;
  const float4 v = *(const float4*)(src + q);
  uint2 o;
  o.x = cvt_pk_bf16(v.x, v.y);
  o.y = cvt_pk_bf16(v.z, v.w);
  *(uint2*)(xemb + (size_t)r * 1024 + q) = o;
}

// ---------------- K2: lstm_W -> per-block MFMA-fragment-slot images (bf16) ----------------
// Image for lstm block bid (layer=bid>>7, u0=(bid&127)*8): 8192 slots x 16B, slot
// S = kt*128 + tn*64 + lane ; content = W[kt*32 + (lane>>4)*8 .. +8][gcol] as 8 bf16,
// where c = tn*16 + (lane&15), gcol = (c>>3)*1024 + u0 + (c&7).
__global__ __launch_bounds__(256) void reorg_lstm_w(
    const float* __restrict__ W, char* __restrict__ wimg)
{
  __shared__ float tile[64 * 36];
  const int bid = blockIdx.x;            // 256 = lstm block id
  const int layer = bid >> 7;
  const int u0 = (bid & 127) * 8;
  const int tid = threadIdx.x;
  const float* Wl = W + (size_t)layer * 2048 * 4096;
  char* img = wimg + (size_t)bid * 131072;
  const int kl = tid >> 2, g = tid & 3;                                  // load map
  const int row = tid & 15, ksub = (tid >> 4) & 3;                       // emit map
  const int tn = (tid >> 6) & 1, kl2 = tid >> 7;
  const int c = tn * 16 + row;
#pragma unroll 1
  for (int kt = 0; kt < 32; ++kt) {
    const float* src = Wl + (size_t)(kt * 64 + kl) * 4096 + g * 1024 + u0;
    const float4 v0 = *(const float4*)src;
    const float4 v1 = *(const float4*)(src + 4);
    *(float4*)(tile + kl * 36 + g * 8) = v0;
    *(float4*)(tile + kl * 36 + g * 8 + 4) = v1;
    __syncthreads();
    const int kbase = kl2 * 32 + ksub * 8;
    uint4 u;
    u.x = cvt_pk_bf16(tile[(kbase + 0) * 36 + c], tile[(kbase + 1) * 36 + c]);
    u.y = cvt_pk_bf16(tile[(kbase + 2) * 36 + c], tile[(kbase + 3) * 36 + c]);
    u.z = cvt_pk_bf16(tile[(kbase + 4) * 36 + c], tile[(kbase + 5) * 36 + c]);
    u.w = cvt_pk_bf16(tile[(kbase + 6) * 36 + c], tile[(kbase + 7) * 36 + c]);
    const int S = (kt * 2 + kl2) * 128 + tn * 64 + ksub * 16 + row;
    *(uint4*)(img + (size_t)S * 16) = u;
    __syncthreads();
  }
}

// ---------------- K3: pipelined 2-layer LSTM scan ----------------
// 256 blocks x 512 threads, 1/CU. Block: layer=bid>>7, 32 gate-cols at u0=(bid&127)*8.
// Wave w: tb=w&1 (16 batch rows), kq=w>>1 (512-K quarter).
// Barrier: 8 monotone counters in one 32B line; arrive = 1 remote atomic inc; all threads
// poll min-of-8 >= 32*p. Static x (layer0 low-K, xemb) prefetched into VGPRs pre-poll;
// coherent x (h buffers) issued post-poll with counted vmcnt(12/8/4/0) MFMA interleave.
__global__ __launch_bounds__(512, 1) void lstm_seq_kernel(
    const char* __restrict__ wimg, const float* __restrict__ bias,
    const float* __restrict__ c0_in,
    const unsigned short* __restrict__ xemb,
    unsigned short* __restrict__ h0buf, unsigned short* __restrict__ h1buf,
    unsigned short* __restrict__ hseq,
    float* __restrict__ out_tail, int* __restrict__ bar)
{
  __shared__ __align__(16) char smem[148608];
  char* wlds   = smem;                        // 131072: W fragment slots
  float* red   = (float*)(smem + 131072);     //  12288: K-quarter partials (12 x 64 x f32x4)
  float* gates = (float*)(smem + 143360);     //   4224: [32 b][33] padded
  float* cl    = (float*)(smem + 147584);     //   1024: c-state [32 b][8 u]

  const int tid = threadIdx.x;
  const int bid = blockIdx.x;
  const int layer = bid >> 7;
  const int u0 = (bid & 127) * 8;
  const int lane = tid & 63, w = tid >> 6;
  const int tb = w & 1, kq = w >> 1;
  const int row = tb * 16 + (lane & 15);
  const int kg = lane >> 4;
  unsigned short* hmy = layer ? h1buf : h0buf;
  unsigned* barp = (unsigned*)bar;
  const bool statx = (layer == 0) && (kq < 2);   // static xemb operand (prefetchable)

  // one-time: W image -> LDS (linear 16B, coalesced), c-state -> LDS
  {
    const char* img = wimg + (size_t)bid * 131072;
#pragma unroll 1
    for (int i = 0; i < 16; ++i) {
      const int off = (i * 512 + tid) * 16;
      __builtin_amdgcn_global_load_lds((gas_ptr)(img + off), (las_ptr)(wlds + off), 16, 0, 0);
    }
    if (tid < 256) cl[tid] = c0_in[layer * 32768 + (tid >> 3) * 1024 + u0 + (tid & 7)];
  }
  const int cc = lane & 15;
  const float biasv0 = bias[layer * 4096 + (cc >> 3) * 1024 + u0 + (cc & 7)];         // tn=0 col
  const float biasv1 = bias[layer * 4096 + ((cc + 16) >> 3) * 1024 + u0 + (cc & 7)];  // tn=1 col
  asm volatile("s_waitcnt vmcnt(0)");
  __syncthreads();

  const char* wq = wlds + (size_t)(kq * 16 * 128 + lane) * 16;

  bf16x8 a[16];
  if (statx) {  // prefetch t=0 fragments
    const char* xn = (const char*)xemb + row * 2048 + kq * 1024 + kg * 16;
#pragma unroll
    for (int j = 0; j < 16; ++j) a[j] = *(const bf16x8*)(xn + j * 64);
  }

  for (int p = 0; p <= 128; ++p) {
    if (p > 0) {  // ---- poll: all 8 counters >= 32*p (all threads; wave-uniform) ----
      const unsigned tgt = 32u * (unsigned)p;
      while (true) {
        u32x4 c0, c1;
        asm volatile(
            "global_load_dwordx4 %0, %2, off sc0 sc1\n\t"
            "global_load_dwordx4 %1, %2, off offset:16 sc0 sc1\n\t"
            "s_waitcnt vmcnt(0)"
            : "=v"(c0), "=v"(c1) : "v"(barp) : "memory");
        const unsigned m = umin2(umin2(umin2(c0[0], c0[1]), umin2(c0[2], c0[3])),
                                 umin2(umin2(c1[0], c1[1]), umin2(c1[2], c1[3])));
        if (m >= tgt) break;
        __builtin_amdgcn_s_sleep(1);
      }
    }

    const bool active = layer ? (p >= 1) : (p < 128);
    if (active) {
      const int t = layer ? (p - 1) : p;
      f32x4 acc0 = {0.f, 0.f, 0.f, 0.f}, acc1 = {0.f, 0.f, 0.f, 0.f};

      if (!statx) {
        // coherent x: layer0 kq>=2 -> own h0; layer1: kq<2 -> h0, kq>=2 -> own h1
        const char* src = (layer && kq < 2) ? (const char*)h0buf : (const char*)hmy;
        const char* xb = src + (p & 1) * 65536 + row * 2048 + (kq & 1) * 1024 + kg * 16;
        // issue all 16 coherent 16B loads
#pragma unroll
        for (int j = 0; j < 16; ++j)
          asm volatile("global_load_dwordx4 %0, %1, off sc0 sc1"
                       : "=v"(a[j]) : "v"(xb + j * 64) : "memory");
        // consume in 4 groups under counted vmcnt (loads retire in issue order)
#pragma unroll
        for (int g = 0; g < 4; ++g) {
          asm volatile("s_waitcnt vmcnt(%0)" :: "n"(12 - 4 * 0) : "memory");  // placeholder, replaced below
          // (the real wait for this group:)
          if (g == 0) asm volatile("s_waitcnt vmcnt(12)" ::: "memory");
          else if (g == 1) asm volatile("s_waitcnt vmcnt(8)" ::: "memory");
          else if (g == 2) asm volatile("s_waitcnt vmcnt(4)" ::: "memory");
          else asm volatile("s_waitcnt vmcnt(0)" ::: "memory");
          __builtin_amdgcn_sched_barrier(0);  // rule #18: keep MFMAs below their wait
#pragma unroll
          for (int j = g * 4; j < g * 4 + 4; ++j) {
            const bf16x8 b0 = *(const bf16x8*)(wq + (size_t)j * 2048);
            const bf16x8 b1 = *(const bf16x8*)(wq + (size_t)j * 2048 + 1024);
            acc0 = __builtin_amdgcn_mfma_f32_16x16x32_bf16(a[j], b0, acc0, 0, 0, 0);
            acc1 = __builtin_amdgcn_mfma_f32_16x16x32_bf16(a[j], b1, acc1, 0, 0, 0);
          }
        }
      } else {
        // static x already in registers (prefetched before the poll)
#pragma unroll
        for (int j = 0; j < 16; ++j) {
          const bf16x8 b0 = *(const bf16x8*)(wq + (size_t)j * 2048);
          const bf16x8 b1 = *(const bf16x8*)(wq + (size_t)j * 2048 + 1024);
          acc0 = __builtin_amdgcn_mfma_f32_16x16x32_bf16(a[j], b0, acc0, 0, 0, 0);
          acc1 = __builtin_amdgcn_mfma_f32_16x16x32_bf16(a[j], b1, acc1, 0, 0, 0);
        }
      }

      // 4-way K-quarter reduction: kq>0 waves dump, kq==0 waves sum + bias -> gates
      if (kq > 0) {
        const int s0 = (((kq - 1) * 2 + tb) * 2 + 0) * 64 + lane;
        const int s1 = (((kq - 1) * 2 + tb) * 2 + 1) * 64 + lane;
        *(f32x4*)(red + s0 * 4) = acc0;
        *(f32x4*)(red + s1 * 4) = acc1;
      }
      __syncthreads();
      if (kq == 0) {
#pragma unroll
        for (int q = 1; q < 4; ++q) {
          const f32x4 o0 = *(const f32x4*)(red + ((((q - 1) * 2 + tb) * 2 + 0) * 64 + lane) * 4);
          const f32x4 o1 = *(const f32x4*)(red + ((((q - 1) * 2 + tb) * 2 + 1) * 64 + lane) * 4);
#pragma unroll
          for (int r = 0; r < 4; ++r) { acc0[r] += o0[r]; acc1[r] += o1[r]; }
        }
        const int rb = tb * 16 + kg * 4;
#pragma unroll
        for (int r = 0; r < 4; ++r) {
          gates[(rb + r) * 33 + cc] = acc0[r] + biasv0;
          gates[(rb + r) * 33 + 16 + cc] = acc1[r] + biasv1;
        }
      }
      __syncthreads();
      // cell update: 128 threads x 2 units; c-state in LDS; h stored as coherent dword
      if (tid < 128) {
        const int cb = tid >> 2, up = (tid & 3) * 2;
        const float gi0 = gates[cb * 33 + up],      gi1 = gates[cb * 33 + up + 1];
        const float gj0 = gates[cb * 33 + 8 + up],  gj1 = gates[cb * 33 + 9 + up];
        const float gf0 = gates[cb * 33 + 16 + up], gf1 = gates[cb * 33 + 17 + up];
        const float go0 = gates[cb * 33 + 24 + up], go1 = gates[cb * 33 + 25 + up];
        const float cn0 = cl[cb * 8 + up] * sigm(gf0) + sigm(gi0) * tanhf(gj0);
        const float cn1 = cl[cb * 8 + up + 1] * sigm(gf1) + sigm(gi1) * tanhf(gj1);
        const float hn0 = tanhf(cn0) * sigm(go0);
        const float hn1 = tanhf(cn1) * sigm(go1);
        cl[cb * 8 + up] = cn0;
        cl[cb * 8 + up + 1] = cn1;
        const unsigned int pk = cvt_pk_bf16(hn0, hn1);
        st_cv((unsigned int*)(hmy + ((p + 1) & 1) * 32768 + cb * 1024 + u0 + up), pk);
        if (layer) *(unsigned int*)(hseq + (size_t)t * 32768 + cb * 1024 + u0 + up) = pk;
        if (t == 127) {
          float* ot = out_tail + layer * 32768 + cb * 1024 + u0 + up;
          ot[0] = hn0; ot[1] = hn1;                     // h_last
          ot[65536] = cn0; ot[65537] = cn1;             // c_last
        }
      }
    }

    if (p < 128) {
      __syncthreads();  // drains h stores (vmcnt 0) before the arrive-inc
      if (tid == 0)
        __hip_atomic_fetch_add(barp + (bid & 7), 1u, __ATOMIC_RELAXED, __HIP_MEMORY_SCOPE_AGENT);
      if (statx && (p + 1) < 128) {  // prefetch next-t xemb frags; complete during poll
        const char* xn = (const char*)xemb + (size_t)(p + 1) * 65536 + row * 2048 + kq * 1024 + kg * 16;
#pragma unroll
        for (int j = 0; j < 16; ++j) a[j] = *(const bf16x8*)(xn + j * 64);
      }
    }
  }
}

// ---------------- K4: dec_W [1024][32000] f32 -> Wt [32000][1024] bf16 ----------------
__global__ __launch_bounds__(256) void transpose_decw_kernel(
    const float* __restrict__ decW, unsigned short* __restrict__ Wt)
{
  __shared__ float tile[64 * 68];
  const int bid = blockIdx.x;         // 8000 = 16 k-tiles x 500 n-tiles
  const int k0 = (bid & 15) * 64;
  const int n0 = (bid >> 4) * 64;
  const int tid = threadIdx.x;
  {
    const int kl = tid >> 4, c4 = (tid & 15) * 4;
#pragma unroll
    for (int i = 0; i < 4; ++i) {
      const int kr = kl + 16 * i;
      *(float4*)(tile + kr * 68 + c4) =
          *(const float4*)(decW + (size_t)(k0 + kr) * 32000 + n0 + c4);
    }
  }
  __syncthreads();
  {
    const int nl = tid >> 3, kc = (tid & 7) * 8;
#pragma unroll
    for (int h2 = 0; h2 < 2; ++h2) {
      const int n = nl + 32 * h2;
      float tv[8];
#pragma unroll
      for (int q = 0; q < 8; ++q) tv[q] = tile[(kc + q) * 68 + n];
      uint4 u;
      u.x = cvt_pk_bf16(tv[0], tv[1]);
      u.y = cvt_pk_bf16(tv[2], tv[3]);
      u.z = cvt_pk_bf16(tv[4], tv[5]);
      u.w = cvt_pk_bf16(tv[6], tv[7]);
      *(uint4*)(Wt + (size_t)(n0 + n) * 1024 + k0 + kc) = u;
    }
  }
}

// ---------------- K5: decoder bf16 MFMA GEMM, 128x128 tile, BK=32, double-buffered ----------------
__global__ __launch_bounds__(256) void decoder_kernel(
    const unsigned short* __restrict__ A,   // hseq  [4096][1024] bf16
    const unsigned short* __restrict__ Bt,  // Wt    [32000][1024] bf16 (dec_W^T)
    const float* __restrict__ decb,
    float* __restrict__ out)                // [4096][32000] f32
{
  __shared__ unsigned short Al[2][128 * 32];
  __shared__ unsigned short Bl[2][128 * 32];

  const int bid = blockIdx.x;
  const int swz = (bid & 7) * 1000 + (bid >> 3);  // XCD-contiguous tile chunks (8000 % 8 == 0)
  const int mt = swz / 250, nt = swz % 250;
  const int m0 = mt * 128, n0 = nt * 128;

  const int tid = threadIdx.x;
  const int lane = tid & 63;
  const int wv = tid >> 6;
  const int wr = wv >> 1, wc = wv & 1;
  const int l15 = lane & 15, kg = lane >> 4;

  f32x4 acc[4][4];
#pragma unroll
  for (int mi = 0; mi < 4; ++mi)
#pragma unroll
    for (int ni = 0; ni < 4; ++ni) {
      f32x4 z = {0.f, 0.f, 0.f, 0.f};
      acc[mi][ni] = z;
    }

  auto stage = [&](const unsigned short* src, int row0, int k0, unsigned short* lds) {
#pragma unroll
    for (int j = 0; j < 2; ++j) {
      const int chunk = (wv * 2 + j) * 64 + lane;   // 512 x 16B per tile
      const int r = chunk >> 2, kc = chunk & 3;
      const unsigned short* g = src + (size_t)(row0 + r) * 1024 + k0 + kc * 8;
      __builtin_amdgcn_global_load_lds((gas_ptr)g, (las_ptr)(lds + chunk * 8), 16, 0, 0);
    }
  };

  stage(A, m0, 0, Al[0]);
  stage(Bt, n0, 0, Bl[0]);
  __syncthreads();

  int buf = 0;
  for (int kt = 0; kt < 32; ++kt) {
    if (kt < 31) {
      stage(A, m0, (kt + 1) * 32, Al[buf ^ 1]);
      stage(Bt, n0, (kt + 1) * 32, Bl[buf ^ 1]);
    }
    bf16x8 a[4], b[4];
#pragma unroll
    for (int mi = 0; mi < 4; ++mi)
      a[mi] = *(const bf16x8*)&Al[buf][(wr * 64 + mi * 16 + l15) * 32 + kg * 8];
#pragma unroll
    for (int ni = 0; ni < 4; ++ni)
      b[ni] = *(const bf16x8*)&Bl[buf][(wc * 64 + ni * 16 + l15) * 32 + kg * 8];
#pragma unroll
    for (int mi = 0; mi < 4; ++mi)
#pragma unroll
      for (int ni = 0; ni < 4; ++ni)
        acc[mi][ni] = __builtin_amdgcn_mfma_f32_16x16x32_bf16(a[mi], b[ni], acc[mi][ni], 0, 0, 0);
    __syncthreads();  // drains vmcnt (stage kt+1 done) + protects buf reuse
    buf ^= 1;
  }

#pragma unroll
  for (int ni = 0; ni < 4; ++ni) {
    const int ocol = n0 + wc * 64 + ni * 16 + l15;   // C/D: col = lane&15
    const float bv = decb[ocol];
#pragma unroll
    for (int mi = 0; mi < 4; ++mi) {
      const int orow = m0 + wr * 64 + mi * 16 + kg * 4;  // row = (lane>>4)*4 + reg
#pragma unroll
      for (int r = 0; r < 4; ++r)
        out[(size_t)(orow + r) * 32000 + ocol] = acc[mi][ni][r] + bv;
    }
  }
}

extern "C" void kernel_launch(void* const* d_in, const int* in_sizes, int n_in,
                              void* d_out, int out_size, void* d_ws, size_t ws_size,
                              hipStream_t stream) {
  (void)in_sizes; (void)n_in; (void)out_size; (void)ws_size;
  const int* tokens  = (const int*)d_in[0];
  const float* h0_in = (const float*)d_in[1];
  const float* c0_in = (const float*)d_in[2];
  const float* etab  = (const float*)d_in[3];
  const float* lstmW = (const float*)d_in[4];
  const float* lstmb = (const float*)d_in[5];
  const float* decW  = (const float*)d_in[6];
  const float* decb  = (const float*)d_in[7];
  float* out = (float*)d_out;

  char* ws = (char*)d_ws;
  unsigned short* hseq  = (unsigned short*)(ws + 0);         //  8,388,608 B
  char* img             = ws + 8388608;                      // 33,554,432 B (lstm phase)
  unsigned short* Wt    = (unsigned short*)(ws + 8388608);   // 65,536,000 B (decoder phase, overlaps img+xemb)
  unsigned short* xemb  = (unsigned short*)(ws + 41943040);  //  8,388,608 B (lstm phase)
  unsigned short* h0buf = (unsigned short*)(ws + 73924608);  //    131,072 B (bf16, 2 slots)
  unsigned short* h1buf = (unsigned short*)(ws + 74055680);  //    131,072 B
  int* bar              = (int*)(ws + 74186752);             //      3,072 B

  init_kernel<<<128, 256, 0, stream>>>(h0_in, h0buf, h1buf, bar);
  gather_emb<<<4096, 256, 0, stream>>>(tokens, etab, xemb);
  reorg_lstm_w<<<256, 256, 0, stream>>>(lstmW, img);
  lstm_seq_kernel<<<256, 512, 0, stream>>>(img, lstmb, c0_in, xemb,
                                           h0buf, h1buf, hseq,
                                           out + 131072000, bar);
  transpose_decw_kernel<<<8000, 256, 0, stream>>>(decW, Wt);
  decoder_kernel<<<8000, 256, 0, stream>>>(hseq, Wt, decb, out);
}

// Round 9
// 1362.428 us; speedup vs baseline: 1.6023x; 1.6023x over previous
//
#include <hip/hip_runtime.h>

typedef __attribute__((ext_vector_type(8))) short bf16x8;
typedef __attribute__((ext_vector_type(4))) float f32x4;
typedef const __attribute__((address_space(1))) void* gas_ptr;
typedef __attribute__((address_space(3))) void* las_ptr;

__device__ __forceinline__ unsigned short f2bf(float f) {
  unsigned int u = __float_as_uint(f);
  return (unsigned short)((u + 0x7fffu + ((u >> 16) & 1u)) >> 16);  // RNE
}
__device__ __forceinline__ unsigned int cvt_pk_bf16(float a, float b) {
  unsigned int r;
  asm volatile("v_cvt_pk_bf16_f32 %0, %1, %2" : "=v"(r) : "v"(a), "v"(b));
  return r;
}
__device__ __forceinline__ float sigm(float x) { return 1.0f / (1.0f + __expf(-x)); }

// device-coherent (sc0 sc1) store: relaxed agent atomic bypasses L1/L2, lands at IF.
__device__ __forceinline__ void st_cv(unsigned int* p, unsigned int v) {
  __hip_atomic_store(p, v, __ATOMIC_RELAXED, __HIP_MEMORY_SCOPE_AGENT);
}

// ---- fence-free two-level grid barrier (R7-measured topology) ----
// Writers and pollers separated: 16 leaf lines (16 incs each), master line (16 incs),
// sense line (1 store, 256 read-only pollers). All relaxed; __syncthreads drains stores.
__device__ __forceinline__ void gbar_arrive(int* bars, int target, int bid) {
  int* leaf  = bars + (bid & 15) * 32;
  int* mcnt  = bars + 512;
  int* sense = bars + 640;
  if (__hip_atomic_fetch_add(leaf, 1, __ATOMIC_RELAXED, __HIP_MEMORY_SCOPE_AGENT) == 15) {
    __hip_atomic_store(leaf, 0, __ATOMIC_RELAXED, __HIP_MEMORY_SCOPE_AGENT);
    if (__hip_atomic_fetch_add(mcnt, 1, __ATOMIC_RELAXED, __HIP_MEMORY_SCOPE_AGENT) == 15) {
      __hip_atomic_store(mcnt, 0, __ATOMIC_RELAXED, __HIP_MEMORY_SCOPE_AGENT);
      __hip_atomic_store(sense, target, __ATOMIC_RELAXED, __HIP_MEMORY_SCOPE_AGENT);
    }
  }
}
__device__ __forceinline__ void gbar_wait(int* bars, int target) {
  int* sense = bars + 640;
  while (__hip_atomic_load(sense, __ATOMIC_RELAXED, __HIP_MEMORY_SCOPE_AGENT) < target)
    __builtin_amdgcn_s_sleep(1);
}

// ---------------- K1: h0 -> bf16 double-buffered state, zero barrier ----------------
__global__ __launch_bounds__(256) void init_kernel(
    const float* __restrict__ h0_in,
    unsigned short* __restrict__ h0buf, unsigned short* __restrict__ h1buf,
    int* __restrict__ bar)
{
  const int j = blockIdx.x * 256 + threadIdx.x;   // 0..32767
  if (j < 768) bar[j] = 0;
  h0buf[j] = f2bf(h0_in[j]);                 // layer0 h -> h0buf slot0
  h1buf[32768 + j] = f2bf(h0_in[32768 + j]); // layer1 h -> h1buf slot1
}

// ---------------- K1b: gather emb[tokens] -> xemb bf16 [128*32][1024] ----------------
__global__ __launch_bounds__(256) void gather_emb(
    const int* __restrict__ tokens, const float* __restrict__ etab,
    unsigned short* __restrict__ xemb)
{
  const int r = blockIdx.x;                       // t*32 + b
  const float* src = etab + (size_t)tokens[r] * 1024;
  const int q = threadIdx.x * 4;
  const float4 v = *(const float4*)(src + q);
  uint2 o;
  o.x = cvt_pk_bf16(v.x, v.y);
  o.y = cvt_pk_bf16(v.z, v.w);
  *(uint2*)(xemb + (size_t)r * 1024 + q) = o;
}

// ---------------- K2: lstm_W -> per-block MFMA-fragment-slot images (bf16) ----------------
// Image for lstm block bid (layer=bid>>7, u0=(bid&127)*8): 8192 slots x 16B, slot
// S = kt*128 + tn*64 + lane ; content = W[kt*32 + (lane>>4)*8 .. +8][gcol] as 8 bf16,
// where c = tn*16 + (lane&15), gcol = (c>>3)*1024 + u0 + (c&7).
__global__ __launch_bounds__(256) void reorg_lstm_w(
    const float* __restrict__ W, char* __restrict__ wimg)
{
  __shared__ float tile[64 * 36];
  const int bid = blockIdx.x;            // 256 = lstm block id
  const int layer = bid >> 7;
  const int u0 = (bid & 127) * 8;
  const int tid = threadIdx.x;
  const float* Wl = W + (size_t)layer * 2048 * 4096;
  char* img = wimg + (size_t)bid * 131072;
  const int kl = tid >> 2, g = tid & 3;                                  // load map
  const int row = tid & 15, ksub = (tid >> 4) & 3;                       // emit map
  const int tn = (tid >> 6) & 1, kl2 = tid >> 7;
  const int c = tn * 16 + row;
#pragma unroll 1
  for (int kt = 0; kt < 32; ++kt) {
    const float* src = Wl + (size_t)(kt * 64 + kl) * 4096 + g * 1024 + u0;
    const float4 v0 = *(const float4*)src;
    const float4 v1 = *(const float4*)(src + 4);
    *(float4*)(tile + kl * 36 + g * 8) = v0;
    *(float4*)(tile + kl * 36 + g * 8 + 4) = v1;
    __syncthreads();
    const int kbase = kl2 * 32 + ksub * 8;
    uint4 u;
    u.x = cvt_pk_bf16(tile[(kbase + 0) * 36 + c], tile[(kbase + 1) * 36 + c]);
    u.y = cvt_pk_bf16(tile[(kbase + 2) * 36 + c], tile[(kbase + 3) * 36 + c]);
    u.z = cvt_pk_bf16(tile[(kbase + 4) * 36 + c], tile[(kbase + 5) * 36 + c]);
    u.w = cvt_pk_bf16(tile[(kbase + 6) * 36 + c], tile[(kbase + 7) * 36 + c]);
    const int S = (kt * 2 + kl2) * 128 + tn * 64 + ksub * 16 + row;
    *(uint4*)(img + (size_t)S * 16) = u;
    __syncthreads();
  }
}

// ---------------- K3: pipelined 2-layer LSTM scan ----------------
// 256 blocks x 512 threads, 1/CU. Block: layer=bid>>7, 32 gate-cols at u0=(bid&127)*8.
// Wave w: tb=w&1 (16 batch rows), kq=w>>1 (512-K quarter).
// R7 barrier topology (leaf/master/sense, relaxed, thread-0 poll). Static xemb fragments
// prefetched into VGPRs between arrive and poll; coherent h loads (sc0 sc1, 16B) consumed
// under counted vmcnt(12/8/4/0) with MFMA interleave.
__global__ __launch_bounds__(512, 1) void lstm_seq_kernel(
    const char* __restrict__ wimg, const float* __restrict__ bias,
    const float* __restrict__ c0_in,
    const unsigned short* __restrict__ xemb,
    unsigned short* __restrict__ h0buf, unsigned short* __restrict__ h1buf,
    unsigned short* __restrict__ hseq,
    float* __restrict__ out_tail, int* __restrict__ bar)
{
  __shared__ __align__(16) char smem[148608];
  char* wlds   = smem;                        // 131072: W fragment slots
  float* red   = (float*)(smem + 131072);     //  12288: K-quarter partials (12 x 64 x f32x4)
  float* gates = (float*)(smem + 143360);     //   4224: [32 b][33] padded
  float* cl    = (float*)(smem + 147584);     //   1024: c-state [32 b][8 u]

  const int tid = threadIdx.x;
  const int bid = blockIdx.x;
  const int layer = bid >> 7;
  const int u0 = (bid & 127) * 8;
  const int lane = tid & 63, w = tid >> 6;
  const int tb = w & 1, kq = w >> 1;
  const int row = tb * 16 + (lane & 15);
  const int kg = lane >> 4;
  unsigned short* hmy = layer ? h1buf : h0buf;
  const bool statx = (layer == 0) && (kq < 2);   // static xemb operand (prefetchable)

  // one-time: W image -> LDS (linear 16B, coalesced), c-state -> LDS
  {
    const char* img = wimg + (size_t)bid * 131072;
#pragma unroll 1
    for (int i = 0; i < 16; ++i) {
      const int off = (i * 512 + tid) * 16;
      __builtin_amdgcn_global_load_lds((gas_ptr)(img + off), (las_ptr)(wlds + off), 16, 0, 0);
    }
    if (tid < 256) cl[tid] = c0_in[layer * 32768 + (tid >> 3) * 1024 + u0 + (tid & 7)];
  }
  const int cc = lane & 15;
  const float biasv0 = bias[layer * 4096 + (cc >> 3) * 1024 + u0 + (cc & 7)];         // tn=0 col
  const float biasv1 = bias[layer * 4096 + ((cc + 16) >> 3) * 1024 + u0 + (cc & 7)];  // tn=1 col
  asm volatile("s_waitcnt vmcnt(0)");
  __syncthreads();

  const char* wq = wlds + (size_t)(kq * 16 * 128 + lane) * 16;

  bf16x8 a[16];
  if (statx) {  // prefetch t=0 fragments (plain cached loads; xemb is static)
    const char* xn = (const char*)xemb + row * 2048 + kq * 1024 + kg * 16;
#pragma unroll
    for (int j = 0; j < 16; ++j) a[j] = *(const bf16x8*)(xn + j * 64);
  }

  for (int p = 0; p <= 128; ++p) {
    const bool active = layer ? (p >= 1) : (p < 128);
    if (active) {
      const int t = layer ? (p - 1) : p;
      f32x4 acc0 = {0.f, 0.f, 0.f, 0.f}, acc1 = {0.f, 0.f, 0.f, 0.f};

      if (!statx) {
        // coherent x: layer0 kq>=2 -> own h0; layer1: kq<2 -> h0, kq>=2 -> own h1
        const char* src = (layer && kq < 2) ? (const char*)h0buf : (const char*)hmy;
        const char* xb = src + (p & 1) * 65536 + row * 2048 + (kq & 1) * 1024 + kg * 16;
        // issue all 16 coherent 16B loads (vmcnt==0 on entry: barrier drained everything)
#pragma unroll
        for (int j = 0; j < 16; ++j)
          asm volatile("global_load_dwordx4 %0, %1, off sc0 sc1"
                       : "=v"(a[j]) : "v"(xb + j * 64) : "memory");
        // consume in 4 groups under counted vmcnt (loads retire in issue order)
        auto mm4 = [&](int j0) {
#pragma unroll
          for (int j = j0; j < j0 + 4; ++j) {
            const bf16x8 b0 = *(const bf16x8*)(wq + (size_t)j * 2048);
            const bf16x8 b1 = *(const bf16x8*)(wq + (size_t)j * 2048 + 1024);
            acc0 = __builtin_amdgcn_mfma_f32_16x16x32_bf16(a[j], b0, acc0, 0, 0, 0);
            acc1 = __builtin_amdgcn_mfma_f32_16x16x32_bf16(a[j], b1, acc1, 0, 0, 0);
          }
        };
        asm volatile("s_waitcnt vmcnt(12)" ::: "memory");
        __builtin_amdgcn_sched_barrier(0);  // rule #18: keep MFMAs below their wait
        mm4(0);
        asm volatile("s_waitcnt vmcnt(8)" ::: "memory");
        __builtin_amdgcn_sched_barrier(0);
        mm4(4);
        asm volatile("s_waitcnt vmcnt(4)" ::: "memory");
        __builtin_amdgcn_sched_barrier(0);
        mm4(8);
        asm volatile("s_waitcnt vmcnt(0)" ::: "memory");
        __builtin_amdgcn_sched_barrier(0);
        mm4(12);
      } else {
        // static x already in registers (prefetched during the previous poll window)
#pragma unroll
        for (int j = 0; j < 16; ++j) {
          const bf16x8 b0 = *(const bf16x8*)(wq + (size_t)j * 2048);
          const bf16x8 b1 = *(const bf16x8*)(wq + (size_t)j * 2048 + 1024);
          acc0 = __builtin_amdgcn_mfma_f32_16x16x32_bf16(a[j], b0, acc0, 0, 0, 0);
          acc1 = __builtin_amdgcn_mfma_f32_16x16x32_bf16(a[j], b1, acc1, 0, 0, 0);
        }
      }

      // 4-way K-quarter reduction: kq>0 waves dump, kq==0 waves sum + bias -> gates
      if (kq > 0) {
        const int s0 = (((kq - 1) * 2 + tb) * 2 + 0) * 64 + lane;
        const int s1 = (((kq - 1) * 2 + tb) * 2 + 1) * 64 + lane;
        *(f32x4*)(red + s0 * 4) = acc0;
        *(f32x4*)(red + s1 * 4) = acc1;
      }
      __syncthreads();
      if (kq == 0) {
#pragma unroll
        for (int q = 1; q < 4; ++q) {
          const f32x4 o0 = *(const f32x4*)(red + ((((q - 1) * 2 + tb) * 2 + 0) * 64 + lane) * 4);
          const f32x4 o1 = *(const f32x4*)(red + ((((q - 1) * 2 + tb) * 2 + 1) * 64 + lane) * 4);
#pragma unroll
          for (int r = 0; r < 4; ++r) { acc0[r] += o0[r]; acc1[r] += o1[r]; }
        }
        const int rb = tb * 16 + kg * 4;
#pragma unroll
        for (int r = 0; r < 4; ++r) {
          gates[(rb + r) * 33 + cc] = acc0[r] + biasv0;
          gates[(rb + r) * 33 + 16 + cc] = acc1[r] + biasv1;
        }
      }
      __syncthreads();
      // cell update: 128 threads x 2 units; c-state in LDS; h stored as coherent dword
      if (tid < 128) {
        const int cb = tid >> 2, up = (tid & 3) * 2;
        const float gi0 = gates[cb * 33 + up],      gi1 = gates[cb * 33 + up + 1];
        const float gj0 = gates[cb * 33 + 8 + up],  gj1 = gates[cb * 33 + 9 + up];
        const float gf0 = gates[cb * 33 + 16 + up], gf1 = gates[cb * 33 + 17 + up];
        const float go0 = gates[cb * 33 + 24 + up], go1 = gates[cb * 33 + 25 + up];
        const float cn0 = cl[cb * 8 + up] * sigm(gf0) + sigm(gi0) * tanhf(gj0);
        const float cn1 = cl[cb * 8 + up + 1] * sigm(gf1) + sigm(gi1) * tanhf(gj1);
        const float hn0 = tanhf(cn0) * sigm(go0);
        const float hn1 = tanhf(cn1) * sigm(go1);
        cl[cb * 8 + up] = cn0;
        cl[cb * 8 + up + 1] = cn1;
        const unsigned int pk = cvt_pk_bf16(hn0, hn1);
        st_cv((unsigned int*)(hmy + ((p + 1) & 1) * 32768 + cb * 1024 + u0 + up), pk);
        if (layer) *(unsigned int*)(hseq + (size_t)t * 32768 + cb * 1024 + u0 + up) = pk;
        if (t == 127) {
          float* ot = out_tail + layer * 32768 + cb * 1024 + u0 + up;
          ot[0] = hn0; ot[1] = hn1;                     // h_last
          ot[65536] = cn0; ot[65537] = cn1;             // c_last
        }
      }
    }

    if (p < 128) {
      __syncthreads();  // all LDS consumers done; drains h stores (vmcnt 0) before arrive
      if (tid == 0) gbar_arrive(bar, p + 1, bid);
      if (statx && (p + 1) < 128) {
        // prefetch next-t xemb frags; they fly during the poll, land at exit syncthreads
        const char* xn = (const char*)xemb + (size_t)(p + 1) * 65536 + row * 2048 + kq * 1024 + kg * 16;
#pragma unroll
        for (int j = 0; j < 16; ++j) a[j] = *(const bf16x8*)(xn + j * 64);
      }
      if (tid == 0) gbar_wait(bar, p + 1);
      __syncthreads();
    }
  }
}

// ---------------- K4: dec_W [1024][32000] f32 -> Wt [32000][1024] bf16 ----------------
__global__ __launch_bounds__(256) void transpose_decw_kernel(
    const float* __restrict__ decW, unsigned short* __restrict__ Wt)
{
  __shared__ float tile[64 * 68];
  const int bid = blockIdx.x;         // 8000 = 16 k-tiles x 500 n-tiles
  const int k0 = (bid & 15) * 64;
  const int n0 = (bid >> 4) * 64;
  const int tid = threadIdx.x;
  {
    const int kl = tid >> 4, c4 = (tid & 15) * 4;
#pragma unroll
    for (int i = 0; i < 4; ++i) {
      const int kr = kl + 16 * i;
      *(float4*)(tile + kr * 68 + c4) =
          *(const float4*)(decW + (size_t)(k0 + kr) * 32000 + n0 + c4);
    }
  }
  __syncthreads();
  {
    const int nl = tid >> 3, kc = (tid & 7) * 8;
#pragma unroll
    for (int h2 = 0; h2 < 2; ++h2) {
      const int n = nl + 32 * h2;
      float tv[8];
#pragma unroll
      for (int q = 0; q < 8; ++q) tv[q] = tile[(kc + q) * 68 + n];
      uint4 u;
      u.x = cvt_pk_bf16(tv[0], tv[1]);
      u.y = cvt_pk_bf16(tv[2], tv[3]);
      u.z = cvt_pk_bf16(tv[4], tv[5]);
      u.w = cvt_pk_bf16(tv[6], tv[7]);
      *(uint4*)(Wt + (size_t)(n0 + n) * 1024 + k0 + kc) = u;
    }
  }
}

// ---------------- K5: decoder bf16 MFMA GEMM, 128x128 tile, BK=32, double-buffered ----------------
__global__ __launch_bounds__(256) void decoder_kernel(
    const unsigned short* __restrict__ A,   // hseq  [4096][1024] bf16
    const unsigned short* __restrict__ Bt,  // Wt    [32000][1024] bf16 (dec_W^T)
    const float* __restrict__ decb,
    float* __restrict__ out)                // [4096][32000] f32
{
  __shared__ unsigned short Al[2][128 * 32];
  __shared__ unsigned short Bl[2][128 * 32];

  const int bid = blockIdx.x;
  const int swz = (bid & 7) * 1000 + (bid >> 3);  // XCD-contiguous tile chunks (8000 % 8 == 0)
  const int mt = swz / 250, nt = swz % 250;
  const int m0 = mt * 128, n0 = nt * 128;

  const int tid = threadIdx.x;
  const int lane = tid & 63;
  const int wv = tid >> 6;
  const int wr = wv >> 1, wc = wv & 1;
  const int l15 = lane & 15, kg = lane >> 4;

  f32x4 acc[4][4];
#pragma unroll
  for (int mi = 0; mi < 4; ++mi)
#pragma unroll
    for (int ni = 0; ni < 4; ++ni) {
      f32x4 z = {0.f, 0.f, 0.f, 0.f};
      acc[mi][ni] = z;
    }

  auto stage = [&](const unsigned short* src, int row0, int k0, unsigned short* lds) {
#pragma unroll
    for (int j = 0; j < 2; ++j) {
      const int chunk = (wv * 2 + j) * 64 + lane;   // 512 x 16B per tile
      const int r = chunk >> 2, kc = chunk & 3;
      const unsigned short* g = src + (size_t)(row0 + r) * 1024 + k0 + kc * 8;
      __builtin_amdgcn_global_load_lds((gas_ptr)g, (las_ptr)(lds + chunk * 8), 16, 0, 0);
    }
  };

  stage(A, m0, 0, Al[0]);
  stage(Bt, n0, 0, Bl[0]);
  __syncthreads();

  int buf = 0;
  for (int kt = 0; kt < 32; ++kt) {
    if (kt < 31) {
      stage(A, m0, (kt + 1) * 32, Al[buf ^ 1]);
      stage(Bt, n0, (kt + 1) * 32, Bl[buf ^ 1]);
    }
    bf16x8 a[4], b[4];
#pragma unroll
    for (int mi = 0; mi < 4; ++mi)
      a[mi] = *(const bf16x8*)&Al[buf][(wr * 64 + mi * 16 + l15) * 32 + kg * 8];
#pragma unroll
    for (int ni = 0; ni < 4; ++ni)
      b[ni] = *(const bf16x8*)&Bl[buf][(wc * 64 + ni * 16 + l15) * 32 + kg * 8];
#pragma unroll
    for (int mi = 0; mi < 4; ++mi)
#pragma unroll
      for (int ni = 0; ni < 4; ++ni)
        acc[mi][ni] = __builtin_amdgcn_mfma_f32_16x16x32_bf16(a[mi], b[ni], acc[mi][ni], 0, 0, 0);
    __syncthreads();  // drains vmcnt (stage kt+1 done) + protects buf reuse
    buf ^= 1;
  }

#pragma unroll
  for (int ni = 0; ni < 4; ++ni) {
    const int ocol = n0 + wc * 64 + ni * 16 + l15;   // C/D: col = lane&15
    const float bv = decb[ocol];
#pragma unroll
    for (int mi = 0; mi < 4; ++mi) {
      const int orow = m0 + wr * 64 + mi * 16 + kg * 4;  // row = (lane>>4)*4 + reg
#pragma unroll
      for (int r = 0; r < 4; ++r)
        out[(size_t)(orow + r) * 32000 + ocol] = acc[mi][ni][r] + bv;
    }
  }
}

extern "C" void kernel_launch(void* const* d_in, const int* in_sizes, int n_in,
                              void* d_out, int out_size, void* d_ws, size_t ws_size,
                              hipStream_t stream) {
  (void)in_sizes; (void)n_in; (void)out_size; (void)ws_size;
  const int* tokens  = (const int*)d_in[0];
  const float* h0_in = (const float*)d_in[1];
  const float* c0_in = (const float*)d_in[2];
  const float* etab  = (const float*)d_in[3];
  const float* lstmW = (const float*)d_in[4];
  const float* lstmb = (const float*)d_in[5];
  const float* decW  = (const float*)d_in[6];
  const float* decb  = (const float*)d_in[7];
  float* out = (float*)d_out;

  char* ws = (char*)d_ws;
  unsigned short* hseq  = (unsigned short*)(ws + 0);         //  8,388,608 B
  char* img             = ws + 8388608;                      // 33,554,432 B (lstm phase)
  unsigned short* Wt    = (unsigned short*)(ws + 8388608);   // 65,536,000 B (decoder phase, overlaps img+xemb)
  unsigned short* xemb  = (unsigned short*)(ws + 41943040);  //  8,388,608 B (lstm phase)
  unsigned short* h0buf = (unsigned short*)(ws + 73924608);  //    131,072 B (bf16, 2 slots)
  unsigned short* h1buf = (unsigned short*)(ws + 74055680);  //    131,072 B
  int* bar              = (int*)(ws + 74186752);             //      3,072 B

  init_kernel<<<128, 256, 0, stream>>>(h0_in, h0buf, h1buf, bar);
  gather_emb<<<4096, 256, 0, stream>>>(tokens, etab, xemb);
  reorg_lstm_w<<<256, 256, 0, stream>>>(lstmW, img);
  lstm_seq_kernel<<<256, 512, 0, stream>>>(img, lstmb, c0_in, xemb,
                                           h0buf, h1buf, hseq,
                                           out + 131072000, bar);
  transpose_decw_kernel<<<8000, 256, 0, stream>>>(decW, Wt);
  decoder_kernel<<<8000, 256, 0, stream>>>(hseq, Wt, decb, out);
}